// Round 4
// baseline (1288.990 us; speedup 1.0000x reference)
//
#include <hip/hip_runtime.h>
#include <math.h>

#define N_RELS 1315
#define NB 65536
#define NNZV (1 << 20)
#define FEATD 768

#define NBUK 256       // row buckets (256 rows each)
#define CAP  5120      // bin capacity per (matrix,bucket); expected 4096, sigma 64
#define CHUNK 4096     // edges per k_bin block
#define STG  2048      // edges per stage
#define EPT  8         // edges per thread per stage (256 threads)

typedef float f32x4 __attribute__((ext_vector_type(4)));
typedef short s16x8 __attribute__((ext_vector_type(8)));
typedef float v2f  __attribute__((ext_vector_type(2)));

struct Mats { const int* rows[6]; const int* cols[6]; const float* vals[6]; };

__device__ __forceinline__ short f2bf(float f) {
    return __builtin_bit_cast(short, (__bf16)f);
}

// ---------------- precompute: P tables, Prel, b' ----------------
__global__ void k_prep(const float* __restrict__ rel_emb,
                       const float* __restrict__ W_in, const float* __restrict__ b_in,
                       const float* __restrict__ W_out, const float* __restrict__ b_out,
                       const float* __restrict__ W_ent, const float* __restrict__ b_ent,
                       const float* __restrict__ W_rel, const float* __restrict__ b_rel,
                       float* __restrict__ Pcat, float* __restrict__ Prel,
                       float* __restrict__ bprime)
{
    __shared__ float C[2][32][33];
    const int tid = threadIdx.x;
    for (int idx = tid; idx < 2 * 32 * 32; idx += 256) {
        int d = idx >> 10, o = (idx >> 5) & 31, t = idx & 31;
        const float* W  = d ? W_out : W_in;
        const float* we = W_ent + o * 832 + 768 + d * 32;
        float s = 0.f;
        #pragma unroll
        for (int j = 0; j < 32; ++j) s += we[j] * W[j * 32 + t];
        C[d][o][t] = s;
    }
    __syncthreads();

    const int row8 = blockIdx.x * 8 + (tid >> 5);
    const int o = tid & 31;
    if (row8 < 2 * N_RELS) {
        const int d = (row8 >= N_RELS) ? 1 : 0;
        const int r = row8 - d * N_RELS;
        const float* re = rel_emb + r * 32;
        float s = 0.f;
        #pragma unroll
        for (int t = 0; t < 32; ++t) s += re[t] * C[d][o][t];
        Pcat[row8 * 32 + o] = s;
    } else if (row8 < 3 * N_RELS) {
        const int r = row8 - 2 * N_RELS;
        const float* re = rel_emb + r * 32;
        float s = b_rel[o];
        #pragma unroll
        for (int j = 0; j < 32; ++j) s += W_rel[o * 32 + j] * re[j];
        float sq = s * s;
        #pragma unroll
        for (int m = 16; m; m >>= 1) sq += __shfl_xor(sq, m);
        Prel[r * 32 + o] = s / fmaxf(sqrtf(sq), 1e-12f);
    }
    if (blockIdx.x == 0 && tid < 32) {
        float s = b_ent[tid];
        #pragma unroll
        for (int j = 0; j < 32; ++j)
            s += b_in[j] * W_ent[tid * 832 + 768 + j] + b_out[j] * W_ent[tid * 832 + 800 + j];
        bprime[tid] = s;
    }
}

// ---------------- pack W_ent[:, :768] into bf16 B-fragments ----------------
__global__ void k_wfrag(const float* __restrict__ W_ent, s16x8* __restrict__ wsB)
{
    const int t = blockIdx.x * 256 + threadIdx.x;
    if (t >= 24 * 2 * 64) return;
    const int kk = t >> 7, rem = t & 127, nt = rem >> 6, l = rem & 63;
    const int col = nt * 16 + (l & 15);
    const int k0  = kk * 32 + ((l >> 4) << 3);
    const float* w = W_ent + col * 832 + k0;
    s16x8 v;
    #pragma unroll
    for (int e = 0; e < 8; ++e) v[e] = f2bf(w[e]);
    wsB[t] = v;
}

// ---------------- cursor init ----------------
__global__ void k_cursor(unsigned* __restrict__ cursor)
{
    const int i = blockIdx.x * 256 + threadIdx.x;
    if (i < 6 * NBUK) cursor[i] = (unsigned)i * CAP;
}

// ---------------- bin edges by row bucket ----------------
__global__ __launch_bounds__(256) void k_bin(Mats m, uint2* __restrict__ bins,
                                             unsigned* __restrict__ cursor)
{
    __shared__ unsigned lcnt[NBUK];
    __shared__ unsigned gbase[NBUK];
    const int mm    = blockIdx.x >> 8;      // 6 matrices x 256 chunks
    const int chunk = blockIdx.x & 255;
    const int tid   = threadIdx.x;
    const int* __restrict__ R = m.rows[mm];
    const int* __restrict__ C = m.cols[mm];
    const float* __restrict__ V = m.vals[mm];
    const int base = chunk * CHUNK;

    for (int st = 0; st < CHUNK / STG; ++st) {
        for (int i = tid; i < NBUK; i += 256) lcnt[i] = 0;
        __syncthreads();
        unsigned meta[EPT]; float val[EPT]; unsigned short lrank[EPT]; unsigned char buk[EPT];
        #pragma unroll
        for (int e = 0; e < EPT; ++e) {
            const int idx = base + st * STG + e * 256 + tid;
            const int row = R[idx];
            const int col = C[idx];
            val[e]  = V[idx];
            buk[e]  = (unsigned char)(row >> 8);
            meta[e] = ((unsigned)(row & 255) << 11) | (unsigned)col;
            lrank[e] = (unsigned short)atomicAdd(&lcnt[buk[e]], 1u);
        }
        __syncthreads();
        gbase[tid] = atomicAdd(&cursor[mm * NBUK + tid], lcnt[tid]);
        __syncthreads();
        #pragma unroll
        for (int e = 0; e < EPT; ++e)
            bins[gbase[buk[e]] + lrank[e]] = make_uint2(meta[e], __float_as_uint(val[e]));
        __syncthreads();
    }
}

// ---------------- per-bucket LDS reduce: aggY[set][rows of bucket] ----------------
// Each 32-lane half-wave loads 32 edges coalesced (prefetched one batch ahead),
// then shuffle-broadcasts each edge; P-row loads are 8-deep in flight; ds_add
// is bank-conflict-free (bank = lane&31).
__global__ __launch_bounds__(512) void k_acc(const uint2* __restrict__ bins,
                                             const unsigned* __restrict__ cursor,
                                             const float* __restrict__ Pcat,
                                             float* __restrict__ aggY)
{
    __shared__ float acc[256 * 32];   // 32 KB
    const int set = blockIdx.x >> 8;  // 3 sets x 256 buckets
    const int b   = blockIdx.x & 255;
    const int tid = threadIdx.x;
    for (int i = tid; i < 256 * 32; i += 512) acc[i] = 0.f;
    __syncthreads();

    const int hw = tid >> 5;          // half-wave id 0..15
    const int c  = tid & 31;          // component / lane-in-half
    for (int dir = 0; dir < 2; ++dir) {
        const int mm = set * 2 + dir;
        const unsigned segbase = (unsigned)(mm * NBUK + b) * CAP;
        const uint2* __restrict__ seg = bins + segbase;
        const int len = (int)(cursor[mm * NBUK + b] - segbase);
        const float* __restrict__ P = Pcat + (size_t)dir * N_RELS * 32;
        const int nbatch = (len + 31) >> 5;   // 32-edge batches

        int pos0 = (hw << 5) + c;
        uint2 ed = (pos0 < len) ? seg[pos0] : make_uint2(0u, 0u);
        for (int t = hw; t < nbatch; t += 16) {
            const int pnxt = ((t + 16) << 5) + c;
            uint2 nxt = (pnxt < len) ? seg[pnxt] : make_uint2(0u, 0u);
            #pragma unroll 8
            for (int j = 0; j < 32; ++j) {
                const unsigned mt = __shfl(ed.x, j, 32);
                const float    v  = __uint_as_float(__shfl(ed.y, j, 32));
                const float    p  = P[((mt & 2047u) << 5) + c];
                atomicAdd(&acc[((mt >> 11) << 5) + c], v * p);
            }
            ed = nxt;
        }
    }
    __syncthreads();
    // exclusive coalesced store
    float4* dst = reinterpret_cast<float4*>(aggY + ((size_t)set * NB + (size_t)b * 256) * 32);
    const float4* src = reinterpret_cast<const float4*>(acc);
    for (int i = tid; i < 2048; i += 512) dst[i] = src[i];
}

// ---------------- fallback scatter (ws too small) ----------------
__global__ void k_scatter(const int* __restrict__ rows, const int* __restrict__ cols,
                          const float* __restrict__ vals,
                          const float* __restrict__ Ptab, float* __restrict__ accs)
{
    const int stride = gridDim.x * blockDim.x;
    const int total = NNZV << 4;
    for (int g = blockIdx.x * blockDim.x + threadIdx.x; g < total; g += stride) {
        const int c2 = (g & 15) << 1;
        const int i  = g >> 4;
        const int row = rows[i];
        const int col = cols[i];
        const float v = vals[i];
        const float* p = Ptab + (col << 5) + c2;
        const int dst = (row << 5) + c2;
#if defined(__has_builtin) && __has_builtin(__builtin_amdgcn_global_atomic_fadd_v2f32)
        typedef __attribute__((address_space(1))) v2f* v2f_as1;
        v2f pv; pv.x = v * p[0]; pv.y = v * p[1];
        __builtin_amdgcn_global_atomic_fadd_v2f32(
            (v2f_as1)(unsigned long long)(accs + dst), pv);
#else
        atomicAdd(accs + dst,     v * p[0]);
        atomicAdd(accs + dst + 1, v * p[1]);
#endif
    }
}

// ---------------- GEMM: Y[set] = normalize(feat @ W.T + b' + agg) ----------------
__global__ __launch_bounds__(256) void k_gemm(
    const float* __restrict__ feat_h, const float* __restrict__ feat_p,
    const float* __restrict__ feat_n,
    const s16x8* __restrict__ wsB, const float* __restrict__ bprime,
    float* __restrict__ Y)
{
    const int lane = threadIdx.x & 63;
    const int wid  = blockIdx.x * 4 + (threadIdx.x >> 6);
    const int set  = wid >> 12;
    const int tile = wid & 4095;
    const int e0   = tile << 4;
    const float* feat = (set == 0) ? feat_h : ((set == 1) ? feat_p : feat_n);

    const int l15 = lane & 15;
    const int kq  = lane >> 4;

    const float4* ap4 = reinterpret_cast<const float4*>(
        feat + (size_t)(e0 + l15) * FEATD + (kq << 3));
    const s16x8* bp = wsB + lane;

    f32x4 acc0 = {0.f, 0.f, 0.f, 0.f};
    f32x4 acc1 = {0.f, 0.f, 0.f, 0.f};

    float4 a0 = ap4[0], a1 = ap4[1];
    #pragma unroll 4
    for (int kk = 0; kk < 24; ++kk) {
        float4 n0, n1;
        if (kk < 23) { n0 = ap4[(kk + 1) * 8]; n1 = ap4[(kk + 1) * 8 + 1]; }
        const s16x8 b0 = bp[(kk * 2 + 0) << 6];
        const s16x8 b1 = bp[(kk * 2 + 1) << 6];
        s16x8 av;
        av[0] = f2bf(a0.x); av[1] = f2bf(a0.y); av[2] = f2bf(a0.z); av[3] = f2bf(a0.w);
        av[4] = f2bf(a1.x); av[5] = f2bf(a1.y); av[6] = f2bf(a1.z); av[7] = f2bf(a1.w);
        acc0 = __builtin_amdgcn_mfma_f32_16x16x32_bf16(av, b0, acc0, 0, 0, 0);
        acc1 = __builtin_amdgcn_mfma_f32_16x16x32_bf16(av, b1, acc1, 0, 0, 0);
        a0 = n0; a1 = n1;
    }

    float* yrow = Y + (size_t)set * NB * 32;
    const float bp0 = bprime[l15], bp1 = bprime[l15 + 16];
    const int rbase = e0 + (kq << 2);
    #pragma unroll
    for (int e = 0; e < 4; ++e) {
        const int ent = rbase + e;
        float v0 = acc0[e] + bp0 + yrow[ent * 32 + l15];
        float v1 = acc1[e] + bp1 + yrow[ent * 32 + l15 + 16];
        float sq = v0 * v0 + v1 * v1;
        sq += __shfl_xor(sq, 1);
        sq += __shfl_xor(sq, 2);
        sq += __shfl_xor(sq, 4);
        sq += __shfl_xor(sq, 8);
        const float inv = 1.f / fmaxf(sqrtf(sq), 1e-12f);
        yrow[ent * 32 + l15]      = v0 * inv;
        yrow[ent * 32 + l15 + 16] = v1 * inv;
    }
}

// ---------------- scores ----------------
__global__ __launch_bounds__(256) void k_score(const float* __restrict__ Y,
                                               const int* __restrict__ eid,
                                               const float* __restrict__ Prel,
                                               float* __restrict__ out)
{
    const int tid = blockIdx.x * 256 + threadIdx.x;
    const int ent = tid >> 5;
    const int c   = tid & 31;
    const float yh = Y[((size_t)0 * NB + ent) * 32 + c];
    const float yp = Y[((size_t)1 * NB + ent) * 32 + c];
    const float yn = Y[((size_t)2 * NB + ent) * 32 + c];
    const float r  = Prel[(size_t)eid[ent] * 32 + c];
    const float dp = yh + r - yp;
    const float dn = yh + r - yn;
    float sp = dp * dp, sn = dn * dn;
    #pragma unroll
    for (int m = 1; m <= 16; m <<= 1) { sp += __shfl_xor(sp, m); sn += __shfl_xor(sn, m); }
    if (c == 0) { out[ent] = sqrtf(sp); out[NB + ent] = sqrtf(sn); }
}

extern "C" void kernel_launch(void* const* d_in, const int* in_sizes, int n_in,
                              void* d_out, int out_size, void* d_ws, size_t ws_size,
                              hipStream_t stream)
{
    const float* feat_h = (const float*)d_in[6];
    const float* feat_p = (const float*)d_in[13];
    const float* feat_n = (const float*)d_in[20];
    const int*   eid    = (const int*)d_in[21];
    const float* rel_emb = (const float*)d_in[22];
    const float* W_in  = (const float*)d_in[23];
    const float* b_in  = (const float*)d_in[24];
    const float* W_out = (const float*)d_in[25];
    const float* b_out = (const float*)d_in[26];
    const float* W_ent = (const float*)d_in[27];
    const float* b_ent = (const float*)d_in[28];
    const float* W_rel = (const float*)d_in[29];
    const float* b_rel = (const float*)d_in[30];

    char* ws = (char*)d_ws;
    const size_t AGG_B   = (size_t)3 * NB * 32 * 4;          // 25,165,824
    const size_t BINS_B  = (size_t)6 * NBUK * CAP * 8;       // 62,914,560
    const size_t CURS_B  = (size_t)6 * NBUK * 4;
    const size_t PCAT_B  = (size_t)2 * N_RELS * 32 * 4;
    const size_t PREL_B  = (size_t)N_RELS * 32 * 4;
    const size_t BPR_B   = 128;
    const size_t WSB_B   = (size_t)24 * 2 * 64 * 16;
    const bool fast = ws_size >= AGG_B + BINS_B + CURS_B + PCAT_B + PREL_B + BPR_B + WSB_B;

    float*    aggY   = (float*)ws;
    size_t off = AGG_B;
    uint2*    bins   = nullptr;
    unsigned* cursor = nullptr;
    if (fast) { bins = (uint2*)(ws + off); off += BINS_B;
                cursor = (unsigned*)(ws + off); off += CURS_B; }
    float* Pcat   = (float*)(ws + off); off += PCAT_B;
    float* Prel   = (float*)(ws + off); off += PREL_B;
    float* bprime = (float*)(ws + off); off += BPR_B;
    s16x8* wsB    = (s16x8*)(ws + off);

    k_prep<<<(3 * N_RELS + 7) / 8, 256, 0, stream>>>(rel_emb, W_in, b_in, W_out, b_out,
                                                     W_ent, b_ent, W_rel, b_rel,
                                                     Pcat, Prel, bprime);
    k_wfrag<<<12, 256, 0, stream>>>(W_ent, wsB);

    static const int base_idx[6] = {0, 3, 7, 10, 14, 17};
    if (fast) {
        Mats m;
        for (int i = 0; i < 6; ++i) {
            m.rows[i] = (const int*)d_in[base_idx[i]];
            m.cols[i] = (const int*)d_in[base_idx[i] + 1];
            m.vals[i] = (const float*)d_in[base_idx[i] + 2];
        }
        k_cursor<<<6, 256, 0, stream>>>(cursor);
        k_bin<<<6 * 256, 256, 0, stream>>>(m, bins, cursor);
        k_acc<<<3 * 256, 512, 0, stream>>>(bins, cursor, Pcat, aggY);
    } else {
        hipMemsetAsync(aggY, 0, AGG_B, stream);
        for (int mm = 0; mm < 6; ++mm) {
            const int d = mm & 1, s = mm >> 1;
            k_scatter<<<32768, 256, 0, stream>>>((const int*)d_in[base_idx[mm]],
                                                 (const int*)d_in[base_idx[mm] + 1],
                                                 (const float*)d_in[base_idx[mm] + 2],
                                                 Pcat + (size_t)d * N_RELS * 32,
                                                 aggY + (size_t)s * NB * 32);
        }
    }

    k_gemm<<<3072, 256, 0, stream>>>(feat_h, feat_p, feat_n, wsB, bprime, aggY);
    k_score<<<8192, 256, 0, stream>>>(aggY, eid, Prel, (float*)d_out);
}

// Round 5
// 1227.144 us; speedup vs baseline: 1.0504x; 1.0504x over previous
//
#include <hip/hip_runtime.h>
#include <math.h>

#define N_RELS 1315
#define NB 65536
#define NNZV (1 << 20)
#define FEATD 768

#define NBUK 256       // row buckets (256 rows each)
#define CAP  5120      // bin capacity per (matrix,bucket); expected 4096, sigma 64
#define CHUNK 4096     // edges per k_bin block
#define STG  2048      // edges per stage
#define EPT  8         // edges per thread per stage (256 threads)

typedef float f32x4 __attribute__((ext_vector_type(4)));
typedef short s16x8 __attribute__((ext_vector_type(8)));
typedef float v2f  __attribute__((ext_vector_type(2)));

struct Mats { const int* rows[6]; const int* cols[6]; const float* vals[6]; };

__device__ __forceinline__ short f2bf(float f) {
    return __builtin_bit_cast(short, (__bf16)f);
}

// ---------------- precompute: P tables, Prel, b' ----------------
__global__ void k_prep(const float* __restrict__ rel_emb,
                       const float* __restrict__ W_in, const float* __restrict__ b_in,
                       const float* __restrict__ W_out, const float* __restrict__ b_out,
                       const float* __restrict__ W_ent, const float* __restrict__ b_ent,
                       const float* __restrict__ W_rel, const float* __restrict__ b_rel,
                       float* __restrict__ Pcat, float* __restrict__ Prel,
                       float* __restrict__ bprime)
{
    __shared__ float C[2][32][33];
    const int tid = threadIdx.x;
    for (int idx = tid; idx < 2 * 32 * 32; idx += 256) {
        int d = idx >> 10, o = (idx >> 5) & 31, t = idx & 31;
        const float* W  = d ? W_out : W_in;
        const float* we = W_ent + o * 832 + 768 + d * 32;
        float s = 0.f;
        #pragma unroll
        for (int j = 0; j < 32; ++j) s += we[j] * W[j * 32 + t];
        C[d][o][t] = s;
    }
    __syncthreads();

    const int row8 = blockIdx.x * 8 + (tid >> 5);
    const int o = tid & 31;
    if (row8 < 2 * N_RELS) {
        const int d = (row8 >= N_RELS) ? 1 : 0;
        const int r = row8 - d * N_RELS;
        const float* re = rel_emb + r * 32;
        float s = 0.f;
        #pragma unroll
        for (int t = 0; t < 32; ++t) s += re[t] * C[d][o][t];
        Pcat[row8 * 32 + o] = s;
    } else if (row8 < 3 * N_RELS) {
        const int r = row8 - 2 * N_RELS;
        const float* re = rel_emb + r * 32;
        float s = b_rel[o];
        #pragma unroll
        for (int j = 0; j < 32; ++j) s += W_rel[o * 32 + j] * re[j];
        float sq = s * s;
        #pragma unroll
        for (int m = 16; m; m >>= 1) sq += __shfl_xor(sq, m);
        Prel[r * 32 + o] = s / fmaxf(sqrtf(sq), 1e-12f);
    }
    if (blockIdx.x == 0 && tid < 32) {
        float s = b_ent[tid];
        #pragma unroll
        for (int j = 0; j < 32; ++j)
            s += b_in[j] * W_ent[tid * 832 + 768 + j] + b_out[j] * W_ent[tid * 832 + 800 + j];
        bprime[tid] = s;
    }
}

// ---------------- pack W_ent[:, :768] into bf16 B-fragments ----------------
__global__ void k_wfrag(const float* __restrict__ W_ent, s16x8* __restrict__ wsB)
{
    const int t = blockIdx.x * 256 + threadIdx.x;
    if (t >= 24 * 2 * 64) return;
    const int kk = t >> 7, rem = t & 127, nt = rem >> 6, l = rem & 63;
    const int col = nt * 16 + (l & 15);
    const int k0  = kk * 32 + ((l >> 4) << 3);
    const float* w = W_ent + col * 832 + k0;
    s16x8 v;
    #pragma unroll
    for (int e = 0; e < 8; ++e) v[e] = f2bf(w[e]);
    wsB[t] = v;
}

// ---------------- cursor init ----------------
__global__ void k_cursor(unsigned* __restrict__ cursor)
{
    const int i = blockIdx.x * 256 + threadIdx.x;
    if (i < 6 * NBUK) cursor[i] = (unsigned)i * CAP;
}

// ---------------- bin edges by row bucket ----------------
__global__ __launch_bounds__(256) void k_bin(Mats m, uint2* __restrict__ bins,
                                             unsigned* __restrict__ cursor)
{
    __shared__ unsigned lcnt[NBUK];
    __shared__ unsigned gbase[NBUK];
    const int mm    = blockIdx.x >> 8;      // 6 matrices x 256 chunks
    const int chunk = blockIdx.x & 255;
    const int tid   = threadIdx.x;
    const int* __restrict__ R = m.rows[mm];
    const int* __restrict__ C = m.cols[mm];
    const float* __restrict__ V = m.vals[mm];
    const int base = chunk * CHUNK;

    for (int st = 0; st < CHUNK / STG; ++st) {
        for (int i = tid; i < NBUK; i += 256) lcnt[i] = 0;
        __syncthreads();
        unsigned meta[EPT]; float val[EPT]; unsigned short lrank[EPT]; unsigned char buk[EPT];
        #pragma unroll
        for (int e = 0; e < EPT; ++e) {
            const int idx = base + st * STG + e * 256 + tid;
            const int row = R[idx];
            const int col = C[idx];
            val[e]  = V[idx];
            buk[e]  = (unsigned char)(row >> 8);
            meta[e] = ((unsigned)(row & 255) << 11) | (unsigned)col;
            lrank[e] = (unsigned short)atomicAdd(&lcnt[buk[e]], 1u);
        }
        __syncthreads();
        gbase[tid] = atomicAdd(&cursor[mm * NBUK + tid], lcnt[tid]);
        __syncthreads();
        #pragma unroll
        for (int e = 0; e < EPT; ++e)
            bins[gbase[buk[e]] + lrank[e]] = make_uint2(meta[e], __float_as_uint(val[e]));
        __syncthreads();
    }
}

// ---------------- per-bucket LDS reduce: aggY[set][rows of bucket] ----------------
// 16 threads per edge (hardware-broadcast meta load), float2 per thread.
// NO shuffles, NO waited LDS ops in the loop: ds_add_f32 is fire-and-forget,
// loads are independent across iterations -> 8-deep MLP per wave.
__global__ __launch_bounds__(512) void k_acc(const uint2* __restrict__ bins,
                                             const unsigned* __restrict__ cursor,
                                             const float* __restrict__ Pcat,
                                             float* __restrict__ aggY)
{
    __shared__ float acc[256 * 32];   // 32 KB
    const int set = blockIdx.x >> 8;  // 3 sets x 256 buckets
    const int b   = blockIdx.x & 255;
    const int tid = threadIdx.x;
    for (int i = tid; i < 256 * 32; i += 512) acc[i] = 0.f;
    __syncthreads();

    const int eg = tid >> 4;          // edge-group 0..31 (16 threads each)
    const int c2 = (tid & 15) << 1;   // component pair
    for (int dir = 0; dir < 2; ++dir) {
        const int mm = set * 2 + dir;
        const unsigned segbase = (unsigned)(mm * NBUK + b) * CAP;
        const uint2* __restrict__ seg = bins + segbase;
        const int len = (int)(cursor[mm * NBUK + b] - segbase);
        const float* __restrict__ P = Pcat + (size_t)dir * N_RELS * 32;
        #pragma unroll 8
        for (int i = eg; i < len; i += 32) {
            const uint2 ed = seg[i];
            const float v  = __uint_as_float(ed.y);
            const float2 p = *reinterpret_cast<const float2*>(P + ((ed.x & 2047u) << 5) + c2);
            float* dst = &acc[((ed.x >> 11) << 5) + c2];
            atomicAdd(dst,     v * p.x);
            atomicAdd(dst + 1, v * p.y);
        }
    }
    __syncthreads();
    // exclusive coalesced store
    float4* dst4 = reinterpret_cast<float4*>(aggY + ((size_t)set * NB + (size_t)b * 256) * 32);
    const float4* src = reinterpret_cast<const float4*>(acc);
    for (int i = tid; i < 2048; i += 512) dst4[i] = src[i];
}

// ---------------- fallback scatter (ws too small) ----------------
__global__ void k_scatter(const int* __restrict__ rows, const int* __restrict__ cols,
                          const float* __restrict__ vals,
                          const float* __restrict__ Ptab, float* __restrict__ accs)
{
    const int stride = gridDim.x * blockDim.x;
    const int total = NNZV << 4;
    for (int g = blockIdx.x * blockDim.x + threadIdx.x; g < total; g += stride) {
        const int c2 = (g & 15) << 1;
        const int i  = g >> 4;
        const int row = rows[i];
        const int col = cols[i];
        const float v = vals[i];
        const float* p = Ptab + (col << 5) + c2;
        const int dst = (row << 5) + c2;
#if defined(__has_builtin) && __has_builtin(__builtin_amdgcn_global_atomic_fadd_v2f32)
        typedef __attribute__((address_space(1))) v2f* v2f_as1;
        v2f pv; pv.x = v * p[0]; pv.y = v * p[1];
        __builtin_amdgcn_global_atomic_fadd_v2f32(
            (v2f_as1)(unsigned long long)(accs + dst), pv);
#else
        atomicAdd(accs + dst,     v * p[0]);
        atomicAdd(accs + dst + 1, v * p[1]);
#endif
    }
}

// ---------------- GEMM: Y[set] = normalize(feat @ W.T + b' + agg) ----------------
__global__ __launch_bounds__(256) void k_gemm(
    const float* __restrict__ feat_h, const float* __restrict__ feat_p,
    const float* __restrict__ feat_n,
    const s16x8* __restrict__ wsB, const float* __restrict__ bprime,
    float* __restrict__ Y)
{
    const int lane = threadIdx.x & 63;
    const int wid  = blockIdx.x * 4 + (threadIdx.x >> 6);
    const int set  = wid >> 12;
    const int tile = wid & 4095;
    const int e0   = tile << 4;
    const float* feat = (set == 0) ? feat_h : ((set == 1) ? feat_p : feat_n);

    const int l15 = lane & 15;
    const int kq  = lane >> 4;

    const float4* ap4 = reinterpret_cast<const float4*>(
        feat + (size_t)(e0 + l15) * FEATD + (kq << 3));
    const s16x8* bp = wsB + lane;

    f32x4 acc0 = {0.f, 0.f, 0.f, 0.f};
    f32x4 acc1 = {0.f, 0.f, 0.f, 0.f};

    float4 a0 = ap4[0], a1 = ap4[1];
    #pragma unroll 4
    for (int kk = 0; kk < 24; ++kk) {
        float4 n0, n1;
        if (kk < 23) { n0 = ap4[(kk + 1) * 8]; n1 = ap4[(kk + 1) * 8 + 1]; }
        const s16x8 b0 = bp[(kk * 2 + 0) << 6];
        const s16x8 b1 = bp[(kk * 2 + 1) << 6];
        s16x8 av;
        av[0] = f2bf(a0.x); av[1] = f2bf(a0.y); av[2] = f2bf(a0.z); av[3] = f2bf(a0.w);
        av[4] = f2bf(a1.x); av[5] = f2bf(a1.y); av[6] = f2bf(a1.z); av[7] = f2bf(a1.w);
        acc0 = __builtin_amdgcn_mfma_f32_16x16x32_bf16(av, b0, acc0, 0, 0, 0);
        acc1 = __builtin_amdgcn_mfma_f32_16x16x32_bf16(av, b1, acc1, 0, 0, 0);
        a0 = n0; a1 = n1;
    }

    float* yrow = Y + (size_t)set * NB * 32;
    const float bp0 = bprime[l15], bp1 = bprime[l15 + 16];
    const int rbase = e0 + (kq << 2);
    #pragma unroll
    for (int e = 0; e < 4; ++e) {
        const int ent = rbase + e;
        float v0 = acc0[e] + bp0 + yrow[ent * 32 + l15];
        float v1 = acc1[e] + bp1 + yrow[ent * 32 + l15 + 16];
        float sq = v0 * v0 + v1 * v1;
        sq += __shfl_xor(sq, 1);
        sq += __shfl_xor(sq, 2);
        sq += __shfl_xor(sq, 4);
        sq += __shfl_xor(sq, 8);
        const float inv = 1.f / fmaxf(sqrtf(sq), 1e-12f);
        yrow[ent * 32 + l15]      = v0 * inv;
        yrow[ent * 32 + l15 + 16] = v1 * inv;
    }
}

// ---------------- scores ----------------
__global__ __launch_bounds__(256) void k_score(const float* __restrict__ Y,
                                               const int* __restrict__ eid,
                                               const float* __restrict__ Prel,
                                               float* __restrict__ out)
{
    const int tid = blockIdx.x * 256 + threadIdx.x;
    const int ent = tid >> 5;
    const int c   = tid & 31;
    const float yh = Y[((size_t)0 * NB + ent) * 32 + c];
    const float yp = Y[((size_t)1 * NB + ent) * 32 + c];
    const float yn = Y[((size_t)2 * NB + ent) * 32 + c];
    const float r  = Prel[(size_t)eid[ent] * 32 + c];
    const float dp = yh + r - yp;
    const float dn = yh + r - yn;
    float sp = dp * dp, sn = dn * dn;
    #pragma unroll
    for (int m = 1; m <= 16; m <<= 1) { sp += __shfl_xor(sp, m); sn += __shfl_xor(sn, m); }
    if (c == 0) { out[ent] = sqrtf(sp); out[NB + ent] = sqrtf(sn); }
}

extern "C" void kernel_launch(void* const* d_in, const int* in_sizes, int n_in,
                              void* d_out, int out_size, void* d_ws, size_t ws_size,
                              hipStream_t stream)
{
    const float* feat_h = (const float*)d_in[6];
    const float* feat_p = (const float*)d_in[13];
    const float* feat_n = (const float*)d_in[20];
    const int*   eid    = (const int*)d_in[21];
    const float* rel_emb = (const float*)d_in[22];
    const float* W_in  = (const float*)d_in[23];
    const float* b_in  = (const float*)d_in[24];
    const float* W_out = (const float*)d_in[25];
    const float* b_out = (const float*)d_in[26];
    const float* W_ent = (const float*)d_in[27];
    const float* b_ent = (const float*)d_in[28];
    const float* W_rel = (const float*)d_in[29];
    const float* b_rel = (const float*)d_in[30];

    char* ws = (char*)d_ws;
    const size_t AGG_B   = (size_t)3 * NB * 32 * 4;          // 25,165,824
    const size_t BINS_B  = (size_t)6 * NBUK * CAP * 8;       // 62,914,560
    const size_t CURS_B  = (size_t)6 * NBUK * 4;
    const size_t PCAT_B  = (size_t)2 * N_RELS * 32 * 4;
    const size_t PREL_B  = (size_t)N_RELS * 32 * 4;
    const size_t BPR_B   = 128;
    const size_t WSB_B   = (size_t)24 * 2 * 64 * 16;
    const bool fast = ws_size >= AGG_B + BINS_B + CURS_B + PCAT_B + PREL_B + BPR_B + WSB_B;

    float*    aggY   = (float*)ws;
    size_t off = AGG_B;
    uint2*    bins   = nullptr;
    unsigned* cursor = nullptr;
    if (fast) { bins = (uint2*)(ws + off); off += BINS_B;
                cursor = (unsigned*)(ws + off); off += CURS_B; }
    float* Pcat   = (float*)(ws + off); off += PCAT_B;
    float* Prel   = (float*)(ws + off); off += PREL_B;
    float* bprime = (float*)(ws + off); off += BPR_B;
    s16x8* wsB    = (s16x8*)(ws + off);

    k_prep<<<(3 * N_RELS + 7) / 8, 256, 0, stream>>>(rel_emb, W_in, b_in, W_out, b_out,
                                                     W_ent, b_ent, W_rel, b_rel,
                                                     Pcat, Prel, bprime);
    k_wfrag<<<12, 256, 0, stream>>>(W_ent, wsB);

    static const int base_idx[6] = {0, 3, 7, 10, 14, 17};
    if (fast) {
        Mats m;
        for (int i = 0; i < 6; ++i) {
            m.rows[i] = (const int*)d_in[base_idx[i]];
            m.cols[i] = (const int*)d_in[base_idx[i] + 1];
            m.vals[i] = (const float*)d_in[base_idx[i] + 2];
        }
        k_cursor<<<6, 256, 0, stream>>>(cursor);
        k_bin<<<6 * 256, 256, 0, stream>>>(m, bins, cursor);
        k_acc<<<3 * 256, 512, 0, stream>>>(bins, cursor, Pcat, aggY);
    } else {
        hipMemsetAsync(aggY, 0, AGG_B, stream);
        for (int mm = 0; mm < 6; ++mm) {
            const int d = mm & 1, s = mm >> 1;
            k_scatter<<<32768, 256, 0, stream>>>((const int*)d_in[base_idx[mm]],
                                                 (const int*)d_in[base_idx[mm] + 1],
                                                 (const float*)d_in[base_idx[mm] + 2],
                                                 Pcat + (size_t)d * N_RELS * 32,
                                                 aggY + (size_t)s * NB * 32);
        }
    }

    k_gemm<<<3072, 256, 0, stream>>>(feat_h, feat_p, feat_n, wsB, bprime, aggY);
    k_score<<<8192, 256, 0, stream>>>(aggY, eid, Prel, (float*)d_out);
}